// Round 11
// baseline (313.174 us; speedup 1.0000x reference)
//
#include <hip/hip_runtime.h>
#include <hip/hip_bf16.h>

typedef __bf16 bf16x8 __attribute__((ext_vector_type(8)));
typedef float f32x4 __attribute__((ext_vector_type(4)));
typedef unsigned short u16x2 __attribute__((ext_vector_type(2)));
typedef short s16x2 __attribute__((ext_vector_type(2)));
typedef unsigned u32x4 __attribute__((ext_vector_type(4)));
typedef __hip_bfloat16 bf16;

static constexpr int NN = 8192;
static constexpr int DD = 128;
static constexpr int KTOP = 1638;   // int(0.2 * 8192)
static constexpr int KSLICE = 8;    // split-K factor for the AV GEMM
static constexpr int KCH = NN / KSLICE;   // 1024
static constexpr int HW = 2178;     // per-wave hist region: 2 copies x 1089 dwords

// async 16B global->LDS (LDS dest = wave-uniform base + lane*16, HW-added)
__device__ __forceinline__ void gll16(const void* g, void* l) {
  __builtin_amdgcn_global_load_lds((const __attribute__((address_space(1))) void*)g,
                                   (__attribute__((address_space(3))) void*)l, 16, 0, 0);
}

// ---------------- prep: local dtype detect + cvt imp + transpose W ----------------
// NOTE (round-7 post-mortem): split-K epilogue fusion via device-scope fences
// regressed 354->506 us — __threadfence on gfx950 forces per-XCD L2
// writeback/invalidate (non-coherent L2s). Keep kernel-launch boundaries for
// cross-XCD producer/consumer; merge only INDEPENDENT kernels.
__global__ void prep(const unsigned short* __restrict__ xin, const void* __restrict__ imp_in,
                     const void* __restrict__ W1, const void* __restrict__ W2,
                     float* __restrict__ impf,
                     bf16* __restrict__ Wt1, bf16* __restrict__ Wt2,
                     int* __restrict__ flag) {
  __shared__ int cnt_s;
  if (threadIdx.x == 0) cnt_s = 0;
  __syncthreads();
  int c = 0;
  for (int i = threadIdx.x; i < 4096; i += 256) {
    int e = (xin[i] >> 7) & 0xFF;
    if (e >= 0x8A) ++c;
  }
  atomicAdd(&cnt_s, c);
  __syncthreads();
  int isf32 = (cnt_s > 16) ? 1 : 0;
  int b = blockIdx.x;
  if (b == 0) {
    if (threadIdx.x == 0) *flag = isf32;
    for (int i = threadIdx.x; i < NN; i += 256)
      impf[i] = isf32 ? ((const float*)imp_in)[i] : __bfloat162float(((const bf16*)imp_in)[i]);
  } else {
    int w = b - 1;                    // 0,1 -> W1 l=0,1 ; 2,3 -> W2 l=0,1
    const void* srcv = (w < 2 ? W1 : W2);
    bf16* dst = (w < 2 ? Wt1 : Wt2) + (w & 1) * DD * DD;
    int off = (w & 1) * DD * DD;
    for (int f = threadIdx.x; f < DD * DD; f += 256) {
      int n = f >> 7, k = f & 127;
      float v = isf32 ? ((const float*)srcv)[off + k * DD + n]
                      : __bfloat162float(((const bf16*)srcv)[off + k * DD + n]);
      dst[n * DD + k] = __float2bfloat16(v);
    }
  }
}

// per-row L2 normalize -> xnb (bf16) + plain bf16 cast -> xb.
__global__ void rownorm(const void* __restrict__ src, const int* __restrict__ flag, int raw,
                        bf16* __restrict__ xnb, bf16* __restrict__ xb) {
  int wave = threadIdx.x >> 6;
  int lane = threadIdx.x & 63;
  int row = blockIdx.x * 4 + wave;
  float vx, vy;
  if (raw && *flag == 0) {            // raw bf16 input: unpack a pair
    unsigned u = ((const unsigned*)src)[(long)row * 64 + lane];
    vx = __uint_as_float(u << 16);
    vy = __uint_as_float(u & 0xFFFF0000u);
  } else {
    float2 v = ((const float2*)src)[(long)row * 64 + lane];
    vx = v.x; vy = v.y;
  }
  float s = vx * vx + vy * vy;
  for (int off = 1; off < 64; off <<= 1) s += __shfl_xor(s, off);
  float inv = 1.0f / (sqrtf(s) + 1e-8f);
  int c = lane * 2;
  xb[(long)row * DD + c]      = __float2bfloat16(vx);
  xb[(long)row * DD + c + 1]  = __float2bfloat16(vy);
  xnb[(long)row * DD + c]     = __float2bfloat16(vx * inv);
  xnb[(long)row * DD + c + 1] = __float2bfloat16(vy * inv);
}

// ---------------- K=128 GEMM core body (shared-scratch version) ----------------
// sm: >= (128+64)*136*2 bytes. Used by the y_dual path of gemm_sy.
__device__ __forceinline__ void gemm_core(const bf16* __restrict__ A, const bf16* __restrict__ Bt,
                                          long rowA0, long rowB0, int tid,
                                          bf16* __restrict__ Yt,
                                          bf16* __restrict__ RM, long rm_ld,
                                          bf16* sm) {
  bf16 (*lA)[136] = reinterpret_cast<bf16(*)[136]>(sm);
  bf16 (*lB)[136] = reinterpret_cast<bf16(*)[136]>(sm + 128 * 136);
  for (int i = 0; i < 8; ++i) {
    int f = tid + i * 256;
    int r = f >> 4, kg = f & 15;
    *reinterpret_cast<uint4*>(&lA[r][kg * 8]) =
        *reinterpret_cast<const uint4*>(A + (rowA0 + r) * DD + kg * 8);
  }
  for (int i = 0; i < 4; ++i) {
    int f = tid + i * 256;
    int r = f >> 4, kg = f & 15;
    *reinterpret_cast<uint4*>(&lB[r][kg * 8]) =
        *reinterpret_cast<const uint4*>(Bt + (rowB0 + r) * DD + kg * 8);
  }
  __syncthreads();
  int wave = tid >> 6, lane = tid & 63;
  int wm = (wave >> 1) * 64;
  int wn = (wave & 1) * 32;
  int quad = lane >> 4, l16 = lane & 15;
  f32x4 acc[4][2];
  #pragma unroll
  for (int mi = 0; mi < 4; ++mi)
    #pragma unroll
    for (int ni = 0; ni < 2; ++ni) acc[mi][ni] = {0.f, 0.f, 0.f, 0.f};
  #pragma unroll
  for (int ks = 0; ks < 4; ++ks) {
    int kb = ks * 32 + quad * 8;
    bf16x8 af[4], bfr[2];
    #pragma unroll
    for (int mi = 0; mi < 4; ++mi)
      af[mi] = *reinterpret_cast<const bf16x8*>(&lA[wm + mi * 16 + l16][kb]);
    #pragma unroll
    for (int ni = 0; ni < 2; ++ni)
      bfr[ni] = *reinterpret_cast<const bf16x8*>(&lB[wn + ni * 16 + l16][kb]);
    #pragma unroll
    for (int mi = 0; mi < 4; ++mi)
      #pragma unroll
      for (int ni = 0; ni < 2; ++ni)
        acc[mi][ni] = __builtin_amdgcn_mfma_f32_16x16x32_bf16(af[mi], bfr[ni], acc[mi][ni], 0, 0, 0);
  }
  // transposed output: 4 consecutive rows per lane -> one 8B store
  if (Yt) {
    #pragma unroll
    for (int mi = 0; mi < 4; ++mi)
      #pragma unroll
      for (int ni = 0; ni < 2; ++ni) {
        long rowb = rowA0 + wm + mi * 16 + quad * 4;
        long col = rowB0 + wn + ni * 16 + l16;
        bf16 t4[4];
        #pragma unroll
        for (int r = 0; r < 4; ++r) t4[r] = __float2bfloat16(acc[mi][ni][r]);
        *reinterpret_cast<ushort4*>(Yt + col * (long)NN + rowb) =
            *reinterpret_cast<const ushort4*>(t4);
      }
  }
  // row-major output via LDS bounce (reuse lA scratch; MFMA reads are done)
  __syncthreads();
  bf16 (*cs)[72] = reinterpret_cast<bf16(*)[72]>(sm);   // 128x72x2B = 18.4 KB
  #pragma unroll
  for (int mi = 0; mi < 4; ++mi)
    #pragma unroll
    for (int ni = 0; ni < 2; ++ni)
      #pragma unroll
      for (int r = 0; r < 4; ++r)
        cs[wm + mi * 16 + quad * 4 + r][wn + ni * 16 + l16] = __float2bfloat16(acc[mi][ni][r]);
  __syncthreads();
  #pragma unroll
  for (int i = 0; i < 4; ++i) {
    int f = tid + i * 256;          // 1024 segments = 128 rows x 8 (8-col) segs
    int r = f >> 3, sg = f & 7;
    *reinterpret_cast<uint4*>(RM + (rowA0 + r) * rm_ld + rowB0 + sg * 8) =
        *reinterpret_cast<const uint4*>(&cs[r][sg * 8]);
  }
}

// ---------------- symmetric S GEMM body: S = relu(Xn @ Xn^T), tile (bi,bj) ------
// sm: >= 2*128*136*2 bytes. Triangular work (bj>=bi); both copies stored via
// coalesced dwordx4 through dual LDS bounce; mirror values bit-identical.
__device__ __forceinline__ void gemm_s_sym_body(const bf16* __restrict__ Xn,
                                                bf16* __restrict__ S,
                                                int bi, int bj, int tid, bf16* sm) {
  if (bj < bi) return;                 // lower triangle via mirror stores
  bf16 (*lA)[136] = reinterpret_cast<bf16(*)[136]>(sm);
  bf16 (*lB)[136] = reinterpret_cast<bf16(*)[136]>(sm + 128 * 136);
  long rowA0 = (long)bi * 128, rowB0 = (long)bj * 128;
  for (int i = 0; i < 8; ++i) {
    int f = tid + i * 256;
    int r = f >> 4, kg = f & 15;
    *reinterpret_cast<uint4*>(&lA[r][kg * 8]) =
        *reinterpret_cast<const uint4*>(Xn + (rowA0 + r) * DD + kg * 8);
    *reinterpret_cast<uint4*>(&lB[r][kg * 8]) =
        *reinterpret_cast<const uint4*>(Xn + (rowB0 + r) * DD + kg * 8);
  }
  __syncthreads();
  int wave = tid >> 6, lane = tid & 63;
  int wm = (wave >> 1) * 64;
  int wn = (wave & 1) * 64;
  int quad = lane >> 4, l16 = lane & 15;
  f32x4 acc[4][4];
  #pragma unroll
  for (int mi = 0; mi < 4; ++mi)
    #pragma unroll
    for (int ni = 0; ni < 4; ++ni) acc[mi][ni] = {0.f, 0.f, 0.f, 0.f};
  #pragma unroll
  for (int ks = 0; ks < 4; ++ks) {
    int kb = ks * 32 + quad * 8;
    bf16x8 af[4], bfr[4];
    #pragma unroll
    for (int mi = 0; mi < 4; ++mi)
      af[mi] = *reinterpret_cast<const bf16x8*>(&lA[wm + mi * 16 + l16][kb]);
    #pragma unroll
    for (int ni = 0; ni < 4; ++ni)
      bfr[ni] = *reinterpret_cast<const bf16x8*>(&lB[wn + ni * 16 + l16][kb]);
    #pragma unroll
    for (int mi = 0; mi < 4; ++mi)
      #pragma unroll
      for (int ni = 0; ni < 4; ++ni)
        acc[mi][ni] = __builtin_amdgcn_mfma_f32_16x16x32_bf16(af[mi], bfr[ni], acc[mi][ni], 0, 0, 0);
  }
  // relu once; keep bf16 quads for both bounce paths
  ushort4 q4[4][4];                    // [mi][ni] = 4 consecutive rows (quad)
  #pragma unroll
  for (int mi = 0; mi < 4; ++mi)
    #pragma unroll
    for (int ni = 0; ni < 4; ++ni) {
      unsigned short t4[4];
      #pragma unroll
      for (int r = 0; r < 4; ++r) {
        float vv = acc[mi][ni][r];
        vv = vv > 0.f ? vv : 0.f;
        bf16 b = __float2bfloat16(vv);
        t4[r] = *reinterpret_cast<unsigned short*>(&b);
      }
      q4[mi][ni] = *reinterpret_cast<const ushort4*>(t4);
    }
  __syncthreads();   // all waves' MFMA LDS reads done; reuse lA=cs, lB=csT
  bf16 (*cs)[136]  = lA;
  bf16 (*csT)[136] = lB;
  #pragma unroll
  for (int mi = 0; mi < 4; ++mi)
    #pragma unroll
    for (int ni = 0; ni < 4; ++ni) {
      int row = wm + mi * 16 + quad * 4;
      int col = wn + ni * 16 + l16;
      const unsigned short* t4 = reinterpret_cast<const unsigned short*>(&q4[mi][ni]);
      #pragma unroll
      for (int r = 0; r < 4; ++r)
        *reinterpret_cast<unsigned short*>(&cs[row + r][col]) = t4[r];
      *reinterpret_cast<ushort4*>(&csT[col][row]) = q4[mi][ni];
    }
  __syncthreads();
  #pragma unroll
  for (int i = 0; i < 8; ++i) {
    int f = tid + i * 256;          // 2048 segments = 128 rows x 16 (8-col) segs
    int r = f >> 4, sg = f & 15;
    *reinterpret_cast<uint4*>(S + (rowA0 + r) * NN + rowB0 + sg * 8) =
        *reinterpret_cast<const uint4*>(&cs[r][sg * 8]);
  }
  if (bi != bj) {
    #pragma unroll
    for (int i = 0; i < 8; ++i) {
      int f = tid + i * 256;        // mirror tile rows = global rows rowB0..+127
      int r = f >> 4, sg = f & 15;
      *reinterpret_cast<uint4*>(S + (rowB0 + r) * NN + rowA0 + sg * 8) =
          *reinterpret_cast<const uint4*>(&csT[r][sg * 8]);
    }
  }
}

// ---------------- MERGED launch: S-GEMM tiles + both Y GEMMs ----------------
__launch_bounds__(256)
__global__ void gemm_sy(const bf16* __restrict__ Xn, bf16* __restrict__ S,
                        const bf16* __restrict__ xb,
                        const bf16* __restrict__ Wt1, const bf16* __restrict__ Wt2,
                        bf16* __restrict__ Yt1, bf16* __restrict__ Yt2,
                        bf16* __restrict__ Yr1, bf16* __restrict__ Yr2) {
  __shared__ bf16 smem[2 * 128 * 136];   // 69632 B
  if (blockIdx.x < 64) {
    gemm_s_sym_body(Xn, S, blockIdx.y, blockIdx.x, threadIdx.x, smem);
  } else {
    int q = blockIdx.x - 64;             // 0..3: {Y1,Y1,Y2,Y2} x col-half
    int sel = q >> 1, bx = q & 1;
    gemm_core(xb, sel ? Wt2 : Wt1, (long)blockIdx.y * 128, (long)bx * 64, threadIdx.x,
              sel ? Yt2 : Yt1, sel ? Yr2 : Yr1, DD, smem);
  }
}

// ---------------- top-k histogram body (dual-parity-copy LDS histogram) --------
// 5.3M SQ_LDS_BANK_CONFLICT (~22% of kernel time) came from same-address/
// same-bank LDS atomic serialization — cosine sims concentrate in few hundred
// bins. Fix: per wave, TWO histogram copies; even lanes atomic into copy 0,
// odd lanes into copy 1 at +1089 dwords (odd offset -> copy 1's bin b sits on
// bank (b+1)%32, so a hot bin in both copies hits different banks).
// Merge at scan: c[j] = h0 + h1 (integer, exact, bit-identical output).
__device__ __forceinline__ void topk_body(const bf16* __restrict__ S,
                                          unsigned short* __restrict__ kthr,
                                          float* __restrict__ invRsF,
                                          int bid, int tid, unsigned* hist) {
  int wave = tid >> 6, lane = tid & 63;
  long row = (long)bid * 4 + wave;
  unsigned* h0 = hist + wave * HW;     // copy 0: bins 0..1024 (1089 dwords)
  unsigned* h1 = h0 + 1089;            // copy 1: bank-shifted by 1
  #pragma unroll
  for (int j = 0; j < 35; ++j) {
    int idx = lane + j * 64;
    if (idx < HW) h0[idx] = 0;
  }
  __syncthreads();

  unsigned* hp = (lane & 1) ? h1 : h0;
  const uint4* rp = reinterpret_cast<const uint4*>(S + row * NN) + lane;
  unsigned hs = 0;                      // or-accumulator: detects values >= 0x4000
  #pragma unroll
  for (int t = 0; t < 16; ++t) {
    uint4 v = rp[t * 64];
    unsigned a4[4] = {v.x, v.y, v.z, v.w};
    #pragma unroll
    for (int e = 0; e < 4; ++e) {
      unsigned u = a4[e];
      hs |= u;
      // packed per-half: clamp((s16)v - 0x3BFF, 0, 1024)
      s16x2 d = __builtin_bit_cast(s16x2, u) - __builtin_bit_cast(s16x2, 0x3BFF3BFFu);
      d = __builtin_elementwise_max(d, (s16x2)0);
      d = __builtin_elementwise_min(d, (s16x2)1024);
      unsigned bins = __builtin_bit_cast(unsigned, d);
      unsigned blo = bins & 0xFFFFu, bhi = bins >> 16;
      if (blo) atomicAdd(&hp[blo], 1u);
      if (bhi) atomicAdd(&hp[bhi], 1u);
    }
  }
  __syncthreads();   // own-wave atomics complete (conservative; deps are intra-wave)

  // per-lane owned bins [lane*17, lane*17+17): counts + local suffix sums
  unsigned c[17], sfx[17];
  #pragma unroll
  for (int j = 0; j < 17; ++j) c[j] = h0[lane * 17 + j] + h1[lane * 17 + j];
  unsigned run = 0;
  #pragma unroll
  for (int j = 16; j >= 0; --j) { run += c[j]; sfx[j] = run; }
  // inclusive suffix-scan of per-lane totals across lanes
  unsigned incl = sfx[0];
  #pragma unroll
  for (int off = 1; off < 64; off <<= 1) {
    unsigned t = __shfl_down(incl, off);
    incl += (lane + off < 64) ? t : 0u;
  }
  unsigned above = incl - sfx[0];       // total count in bins owned by lanes > lane
  // largest bin (>=1) with suffix-count >= KTOP
  int cand = -1;
  #pragma unroll
  for (int j = 16; j >= 0; --j) {
    int b = lane * 17 + j;
    if (cand < 0 && b >= 1 && above + sfx[j] >= (unsigned)KTOP) cand = b;
  }
  int best = cand;
  #pragma unroll
  for (int off = 1; off < 64; off <<= 1) {
    int t = __shfl_xor(best, off);
    best = t > best ? t : best;
  }
  int thrbin = best >= 1 ? best : 1;    // no qualifying bin -> thr = 0x3C00
  unsigned thr = 0x3BFFu + (unsigned)thrbin;

  // rowsum = sum over kept bins of count * value (exact)
  float fs = 0.f;
  #pragma unroll
  for (int j = 0; j < 17; ++j) {
    int b = lane * 17 + j;
    float val = __uint_as_float((0x3BFFu + (unsigned)b) << 16);
    fs += (b >= thrbin) ? (float)c[j] * val : 0.f;
  }
  // cold path (never taken for this problem): values >= 0x4000 clamped to bin 1024
  if (__ballot(hs & 0x40004000u)) {
    float v1024 = __uint_as_float(0x3FFF0000u);
    #pragma unroll 1
    for (int t = 0; t < 16; ++t) {
      uint4 v = rp[t * 64];
      unsigned a4[4] = {v.x, v.y, v.z, v.w};
      for (int e = 0; e < 4; ++e) {
        unsigned lo = a4[e] & 0xFFFFu, hi = a4[e] >> 16;
        if (lo >= 0x4000u && lo < 0x8000u) fs += __uint_as_float(lo << 16) - v1024;
        if (hi >= 0x4000u && hi < 0x8000u) fs += __uint_as_float(hi << 16) - v1024;
      }
    }
  }
  #pragma unroll
  for (int off = 1; off < 64; off <<= 1) fs += __shfl_xor(fs, off);
  if (lane == 0) {
    invRsF[row] = 1.0f / (fs + 1.0f);
    kthr[row] = (unsigned short)thr;    // raw positive bf16 pattern
  }
}

// ---------------- rank-5 prior reduce body ----------------
__device__ __forceinline__ void prior_reduce_body(const float* __restrict__ impf,
                                                  const bf16* __restrict__ Yt1,
                                                  float* __restrict__ Mt, float* __restrict__ Gt,
                                                  int c, int tid, float* red /*[5][4]*/) {
  float s[5] = {0.f, 0.f, 0.f, 0.f, 0.f};
  bool hasY = (c < 128);
  const bf16* col = Yt1 + (long)(hasY ? c : 0) * NN;
  for (int j = tid; j < NN; j += 256) {
    float d = impf[j];
    float a = __expf(d * d * (-1.0f / 32.0f));
    float p = hasY ? a * __bfloat162float(col[j]) : a;
    #pragma unroll
    for (int t = 0; t < 5; ++t) { s[t] += p; p *= d; }
  }
  #pragma unroll
  for (int t = 0; t < 5; ++t)
    for (int off = 1; off < 64; off <<= 1) s[t] += __shfl_xor(s[t], off);
  int wave = tid >> 6, lane = tid & 63;
  if (lane == 0)
    #pragma unroll
    for (int t = 0; t < 5; ++t) red[t * 4 + wave] = s[t];
  __syncthreads();
  if (tid == 0) {
    #pragma unroll
    for (int t = 0; t < 5; ++t) {
      float v = red[t * 4 + 0] + red[t * 4 + 1] + red[t * 4 + 2] + red[t * 4 + 3];
      if (hasY) Mt[t * 128 + c] = v; else Gt[t] = v;
    }
  }
}

// ---------------- MERGED launch: top-k rows + prior reduce ----------------
__launch_bounds__(256)
__global__ void prior_topk(const float* __restrict__ impf, const bf16* __restrict__ Yt1,
                           float* __restrict__ Mt, float* __restrict__ Gt,
                           const bf16* __restrict__ S, unsigned short* __restrict__ kthr,
                           float* __restrict__ invRsF) {
  __shared__ unsigned smem[4 * HW];     // 34848 B (dual-copy hists; prior uses 20 floats)
  int bid = blockIdx.x;
  if (bid < NN / 4) {
    topk_body(S, kthr, invRsF, bid, threadIdx.x, smem);
  } else {
    prior_reduce_body(impf, Yt1, Mt, Gt, bid - NN / 4, threadIdx.x,
                      reinterpret_cast<float*>(smem));
  }
}

// ---------------- split-K masked AV GEMM: Pacc[s] = (mask(S) @ Y2) over k-slice s ----
__launch_bounds__(256)
__global__ void fused_av_partial(const bf16* __restrict__ S, const bf16* __restrict__ Yt2,
                                 const unsigned short* __restrict__ kthr,
                                 float* __restrict__ Pacc) {
  __shared__ bf16 lS[2][128][64];   // 16 KB per buffer
  __shared__ bf16 lY[2][128][64];   // 16 KB per buffer
  int tid = threadIdx.x;
  int wave = tid >> 6, lane = tid & 63;
  long row0 = (long)blockIdx.x * 128;
  long kbase = (long)blockIdx.y * KCH;
  int quad = lane >> 4, l16 = lane & 15;
  int wm = (wave >> 1) * 64;
  int wn = (wave & 1) * 64;
  int swz = (l16 & 7) << 4;                       // read-side XOR swizzle (bytes)

  int sj = lane >> 3, sseg = lane & 7;
  long swb = (long)((sseg ^ sj) << 4);
  const char* gS[4];
  const char* gY[4];
  #pragma unroll
  for (int j = 0; j < 4; ++j) {
    long srow = row0 + (long)(wave * 4 + j) * 8 + sj;
    gS[j] = (const char*)S + (srow * NN + kbase) * 2 + swb;
    long ycol = (long)(wave * 4 + j) * 8 + sj;
    gY[j] = (const char*)Yt2 + (ycol * (long)NN + kbase) * 2 + swb;
  }
  unsigned pp[4];
  #pragma unroll
  for (int mi = 0; mi < 4; ++mi) {
    unsigned p = kthr[row0 + wm + mi * 16 + l16];
    pp[mi] = (p << 16) | p;
  }
  f32x4 acc[4][4];
  #pragma unroll
  for (int mi = 0; mi < 4; ++mi)
    #pragma unroll
    for (int ni = 0; ni < 4; ++ni) acc[mi][ni] = {0.f, 0.f, 0.f, 0.f};

  constexpr int NT = KCH / 64;   // 16 K-steps
  {
    char* lsb = (char*)&lS[0][0][0];
    char* lyb = (char*)&lY[0][0][0];
    #pragma unroll
    for (int j = 0; j < 4; ++j) { gll16(gS[j], lsb + (wave * 4 + j) * 1024); gS[j] += 128; }
    #pragma unroll
    for (int j = 0; j < 4; ++j) { gll16(gY[j], lyb + (wave * 4 + j) * 1024); gY[j] += 128; }
  }
  #pragma unroll 1
  for (int t = 0; t < NT; ++t) {
    int cur = t & 1;
    if (t + 1 < NT) {
      char* lsb = (char*)&lS[cur ^ 1][0][0];
      char* lyb = (char*)&lY[cur ^ 1][0][0];
      #pragma unroll
      for (int j = 0; j < 4; ++j) { gll16(gS[j], lsb + (wave * 4 + j) * 1024); gS[j] += 128; }
      #pragma unroll
      for (int j = 0; j < 4; ++j) { gll16(gY[j], lyb + (wave * 4 + j) * 1024); gY[j] += 128; }
      asm volatile("s_waitcnt vmcnt(8)" ::: "memory");   // current tile landed; 8 in flight
    } else {
      asm volatile("s_waitcnt vmcnt(0)" ::: "memory");
    }
    __builtin_amdgcn_s_barrier();
    const char* lsb = (const char*)&lS[cur][0][0];
    const char* lyb = (const char*)&lY[cur][0][0];
    #pragma unroll
    for (int ks = 0; ks < 2; ++ks) {
      int cb = ks * 64 + quad * 16;
      int cbs = cb ^ swz;
      bf16x8 av[4], bv[4];
      #pragma unroll
      for (int mi = 0; mi < 4; ++mi) {
        int r = wm + mi * 16 + l16;
        u32x4 uu = *reinterpret_cast<const u32x4*>(lsb + r * 128 + cbs);
        #pragma unroll
        for (int e = 0; e < 4; ++e) {
          unsigned tb = uu[e] | 0x80008000u;
          u16x2 d = __builtin_bit_cast(u16x2, tb) - __builtin_bit_cast(u16x2, pp[mi]);
          s16x2 msk = __builtin_bit_cast(s16x2, d) >> 15;   // 0xFFFF if kept (u>=p)
          uu[e] &= __builtin_bit_cast(unsigned, msk);
        }
        av[mi] = __builtin_bit_cast(bf16x8, uu);
      }
      #pragma unroll
      for (int ni = 0; ni < 4; ++ni) {
        int c = wn + ni * 16 + l16;
        bv[ni] = *reinterpret_cast<const bf16x8*>(lyb + c * 128 + cbs);
      }
      #pragma unroll
      for (int mi = 0; mi < 4; ++mi)
        #pragma unroll
        for (int ni = 0; ni < 4; ++ni)
          acc[mi][ni] = __builtin_amdgcn_mfma_f32_16x16x32_bf16(av[mi], bv[ni], acc[mi][ni], 0, 0, 0);
    }
    __builtin_amdgcn_s_barrier();   // all waves done reading cur before it is re-staged
  }
  float* out = Pacc + (long)blockIdx.y * NN * DD;
  #pragma unroll
  for (int mi = 0; mi < 4; ++mi)
    #pragma unroll
    for (int ni = 0; ni < 4; ++ni)
      #pragma unroll
      for (int r = 0; r < 4; ++r) {
        long row = row0 + wm + mi * 16 + quad * 4 + r;
        int col = wn + ni * 16 + l16;
        out[row * DD + col] = acc[mi][ni][r];
      }
}

// ---------------- epilogue: reduce partials + prior (inline pvec) + leaky ----------
__global__ void epilogue(const float* __restrict__ Pacc, const bf16* __restrict__ Yr1,
                         const bf16* __restrict__ Yr2, const float* __restrict__ Gt,
                         const float* __restrict__ Mt, const float* __restrict__ invRsF,
                         const float* __restrict__ impf,
                         float* __restrict__ Xout, const float* __restrict__ hres,
                         float* __restrict__ outf) {
  int q = blockIdx.x * 256 + threadIdx.x;   // one f32x4 group per thread
  int row = q >> 5, c4 = (q & 31) << 2;
  long i = (long)row * DD + c4;
  f32x4 a4 = {0.f, 0.f, 0.f, 0.f};
  #pragma unroll
  for (int s = 0; s < KSLICE; ++s)
    a4 += *reinterpret_cast<const f32x4*>(&Pacc[((long)s * NN + row) * DD + c4]);
  float d = impf[row];
  float a = __expf(d * d * (-1.0f / 32.0f));
  const float ct[5] = {1.0f, 1.0f / 16.0f, 1.0f / 512.0f, 1.0f / 24576.0f, 1.0f / 1572864.0f};
  float g[5];
  float p = a;
  #pragma unroll
  for (int t = 0; t < 5; ++t) { g[t] = ct[t] * p; p *= d; }
  float rs = 1.0f;  // + eye
  #pragma unroll
  for (int t = 0; t < 5; ++t) rs += g[t] * Gt[t];
  float inv = 1.0f / rs;
  float pv[5];
  #pragma unroll
  for (int t = 0; t < 5; ++t) pv[t] = g[t] * inv;
  float ir = invRsF[row];
  ushort4 y1u = *reinterpret_cast<const ushort4*>(Yr1 + i);
  ushort4 y2u = *reinterpret_cast<const ushort4*>(Yr2 + i);
  const bf16* y1p = reinterpret_cast<const bf16*>(&y1u);
  const bf16* y2p = reinterpret_cast<const bf16*>(&y2u);
  f32x4 res;
  #pragma unroll
  for (int k = 0; k < 4; ++k) {
    float y1 = __bfloat162float(y1p[k]);
    float y2 = __bfloat162float(y2p[k]);
    int col = c4 + k;
    float prior = inv * y1 + pv[0] * Mt[col] + pv[1] * Mt[128 + col] + pv[2] * Mt[256 + col]
                + pv[3] * Mt[384 + col] + pv[4] * Mt[512 + col];
    float v = prior + ir * (a4[k] + y2);
    v = v > 0.f ? v : 0.01f * v;
    res[k] = v;
  }
  if (outf) {
    f32x4 h4 = *reinterpret_cast<const f32x4*>(&hres[i]);
    #pragma unroll
    for (int k = 0; k < 4; ++k) res[k] = res[k] + h4[k] * d;   // d == impf[row]
    *reinterpret_cast<f32x4*>(&outf[i]) = res;
  } else {
    *reinterpret_cast<f32x4*>(&Xout[i]) = res;
  }
}

// ---------------- host ----------------

extern "C" void kernel_launch(void* const* d_in, const int* in_sizes, int n_in,
                              void* d_out, int out_size, void* d_ws, size_t ws_size,
                              hipStream_t stream) {
  const void* x_in   = d_in[0];
  const void* imp_in = d_in[1];
  const void* W1 = d_in[2];
  const void* W2 = d_in[3];
  float* out = (float*)d_out;

  char* ws = (char*)d_ws;
  size_t o = 0;
  auto alloc = [&](size_t bytes) { void* p = ws + o; o += (bytes + 511) & ~511ull; return p; };
  bf16*  Af   = (bf16*)alloc((size_t)NN * NN * 2);    // 134 MB relu'd similarity S
  float* Pacc = (float*)alloc((size_t)KSLICE * NN * DD * 4);  // 32 MB split-K partials
  float* xf1  = (float*)alloc((size_t)NN * DD * 4);   // layer-0 output (= h for residual)
  bf16*  xnb  = (bf16*)alloc((size_t)NN * DD * 2);
  bf16*  xb   = (bf16*)alloc((size_t)NN * DD * 2);
  bf16*  Yt1  = (bf16*)alloc((size_t)NN * DD * 2);    // [128][8192] (x@W1)^T
  bf16*  Yt2  = (bf16*)alloc((size_t)NN * DD * 2);
  bf16*  Yr1  = (bf16*)alloc((size_t)NN * DD * 2);    // [8192][128] row-major copies
  bf16*  Yr2  = (bf16*)alloc((size_t)NN * DD * 2);
  bf16*  Wt1  = (bf16*)alloc((size_t)2 * DD * DD * 2);
  bf16*  Wt2  = (bf16*)alloc((size_t)2 * DD * DD * 2);
  float* impf = (float*)alloc((size_t)NN * 4);
  float* Mt   = (float*)alloc((size_t)5 * 128 * 4);
  float* Gt   = (float*)alloc((size_t)8 * 4);
  float* invRsF = (float*)alloc((size_t)NN * 4);
  unsigned short* kthr = (unsigned short*)alloc((size_t)NN * 2);
  int*   dflag  = (int*)alloc(64);
  (void)ws_size; (void)n_in; (void)in_sizes; (void)out_size;

  prep<<<5, 256, 0, stream>>>((const unsigned short*)x_in, imp_in, W1, W2,
                              impf, Wt1, Wt2, dflag);

  for (int l = 0; l < 2; ++l) {
    rownorm<<<NN / 4, 256, 0, stream>>>(l ? (const void*)xf1 : x_in, dflag, l ? 0 : 1, xnb, xb);
    gemm_sy<<<dim3(68, 64), 256, 0, stream>>>(xnb, Af, xb,
                                              Wt1 + l * DD * DD, Wt2 + l * DD * DD,
                                              Yt1, Yt2, Yr1, Yr2);
    prior_topk<<<NN / 4 + 129, 256, 0, stream>>>(impf, Yt1, Mt, Gt, Af, kthr, invRsF);
    fused_av_partial<<<dim3(NN / 128, KSLICE), 256, 0, stream>>>(Af, Yt2, kthr, Pacc);
    if (l == 0)
      epilogue<<<NN * DD / 1024, 256, 0, stream>>>(Pacc, Yr1, Yr2, Gt, Mt, invRsF, impf,
                                                   xf1, nullptr, nullptr);
    else
      epilogue<<<NN * DD / 1024, 256, 0, stream>>>(Pacc, Yr1, Yr2, Gt, Mt, invRsF, impf,
                                                   nullptr, xf1, out);
  }
}

// Round 12
// 297.784 us; speedup vs baseline: 1.0517x; 1.0517x over previous
//
#include <hip/hip_runtime.h>
#include <hip/hip_bf16.h>

typedef __bf16 bf16x8 __attribute__((ext_vector_type(8)));
typedef float f32x4 __attribute__((ext_vector_type(4)));
typedef unsigned short u16x2 __attribute__((ext_vector_type(2)));
typedef short s16x2 __attribute__((ext_vector_type(2)));
typedef unsigned u32x4 __attribute__((ext_vector_type(4)));
typedef __hip_bfloat16 bf16;

static constexpr int NN = 8192;
static constexpr int DD = 128;
static constexpr int KTOP = 1638;   // int(0.2 * 8192)
static constexpr int KSLICE = 8;    // split-K factor for the AV GEMM
static constexpr int KCH = NN / KSLICE;   // 1024

// async 16B global->LDS (LDS dest = wave-uniform base + lane*16, HW-added)
__device__ __forceinline__ void gll16(const void* g, void* l) {
  __builtin_amdgcn_global_load_lds((const __attribute__((address_space(1))) void*)g,
                                   (__attribute__((address_space(3))) void*)l, 16, 0, 0);
}

// ---------------- prep: local dtype detect + cvt imp + transpose W ----------------
// NOTE (round-7 post-mortem): split-K epilogue fusion via device-scope fences
// regressed 354->506 us — __threadfence on gfx950 forces per-XCD L2
// writeback/invalidate (non-coherent L2s). Keep kernel-launch boundaries for
// cross-XCD producer/consumer; merge only INDEPENDENT kernels.
// NOTE (round-11 post-mortem): dual-parity-copy histogram halved bank conflicts
// (5.3M->2.7M, mechanism confirmed) but doubled LDS 17.4->35.3 KB, cutting
// blocks/CU 8->4 on a LATENCY-bound kernel -> net regression (39.4->45.5 us).
// For latency-bound kernels LDS footprint is the occupancy currency.
__global__ void prep(const unsigned short* __restrict__ xin, const void* __restrict__ imp_in,
                     const void* __restrict__ W1, const void* __restrict__ W2,
                     float* __restrict__ impf,
                     bf16* __restrict__ Wt1, bf16* __restrict__ Wt2,
                     int* __restrict__ flag) {
  __shared__ int cnt_s;
  if (threadIdx.x == 0) cnt_s = 0;
  __syncthreads();
  int c = 0;
  for (int i = threadIdx.x; i < 4096; i += 256) {
    int e = (xin[i] >> 7) & 0xFF;
    if (e >= 0x8A) ++c;
  }
  atomicAdd(&cnt_s, c);
  __syncthreads();
  int isf32 = (cnt_s > 16) ? 1 : 0;
  int b = blockIdx.x;
  if (b == 0) {
    if (threadIdx.x == 0) *flag = isf32;
    for (int i = threadIdx.x; i < NN; i += 256)
      impf[i] = isf32 ? ((const float*)imp_in)[i] : __bfloat162float(((const bf16*)imp_in)[i]);
  } else {
    int w = b - 1;                    // 0,1 -> W1 l=0,1 ; 2,3 -> W2 l=0,1
    const void* srcv = (w < 2 ? W1 : W2);
    bf16* dst = (w < 2 ? Wt1 : Wt2) + (w & 1) * DD * DD;
    int off = (w & 1) * DD * DD;
    for (int f = threadIdx.x; f < DD * DD; f += 256) {
      int n = f >> 7, k = f & 127;
      float v = isf32 ? ((const float*)srcv)[off + k * DD + n]
                      : __bfloat162float(((const bf16*)srcv)[off + k * DD + n]);
      dst[n * DD + k] = __float2bfloat16(v);
    }
  }
}

// per-row L2 normalize -> xnb (bf16) + plain bf16 cast -> xb.
__global__ void rownorm(const void* __restrict__ src, const int* __restrict__ flag, int raw,
                        bf16* __restrict__ xnb, bf16* __restrict__ xb) {
  int wave = threadIdx.x >> 6;
  int lane = threadIdx.x & 63;
  int row = blockIdx.x * 4 + wave;
  float vx, vy;
  if (raw && *flag == 0) {            // raw bf16 input: unpack a pair
    unsigned u = ((const unsigned*)src)[(long)row * 64 + lane];
    vx = __uint_as_float(u << 16);
    vy = __uint_as_float(u & 0xFFFF0000u);
  } else {
    float2 v = ((const float2*)src)[(long)row * 64 + lane];
    vx = v.x; vy = v.y;
  }
  float s = vx * vx + vy * vy;
  for (int off = 1; off < 64; off <<= 1) s += __shfl_xor(s, off);
  float inv = 1.0f / (sqrtf(s) + 1e-8f);
  int c = lane * 2;
  xb[(long)row * DD + c]      = __float2bfloat16(vx);
  xb[(long)row * DD + c + 1]  = __float2bfloat16(vy);
  xnb[(long)row * DD + c]     = __float2bfloat16(vx * inv);
  xnb[(long)row * DD + c + 1] = __float2bfloat16(vy * inv);
}

// ---------------- K=128 GEMM core body (shared-scratch version) ----------------
// sm: >= (128+64)*136*2 bytes. Used by the y_dual path of gemm_sy.
__device__ __forceinline__ void gemm_core(const bf16* __restrict__ A, const bf16* __restrict__ Bt,
                                          long rowA0, long rowB0, int tid,
                                          bf16* __restrict__ Yt,
                                          bf16* __restrict__ RM, long rm_ld,
                                          bf16* sm) {
  bf16 (*lA)[136] = reinterpret_cast<bf16(*)[136]>(sm);
  bf16 (*lB)[136] = reinterpret_cast<bf16(*)[136]>(sm + 128 * 136);
  for (int i = 0; i < 8; ++i) {
    int f = tid + i * 256;
    int r = f >> 4, kg = f & 15;
    *reinterpret_cast<uint4*>(&lA[r][kg * 8]) =
        *reinterpret_cast<const uint4*>(A + (rowA0 + r) * DD + kg * 8);
  }
  for (int i = 0; i < 4; ++i) {
    int f = tid + i * 256;
    int r = f >> 4, kg = f & 15;
    *reinterpret_cast<uint4*>(&lB[r][kg * 8]) =
        *reinterpret_cast<const uint4*>(Bt + (rowB0 + r) * DD + kg * 8);
  }
  __syncthreads();
  int wave = tid >> 6, lane = tid & 63;
  int wm = (wave >> 1) * 64;
  int wn = (wave & 1) * 32;
  int quad = lane >> 4, l16 = lane & 15;
  f32x4 acc[4][2];
  #pragma unroll
  for (int mi = 0; mi < 4; ++mi)
    #pragma unroll
    for (int ni = 0; ni < 2; ++ni) acc[mi][ni] = {0.f, 0.f, 0.f, 0.f};
  #pragma unroll
  for (int ks = 0; ks < 4; ++ks) {
    int kb = ks * 32 + quad * 8;
    bf16x8 af[4], bfr[2];
    #pragma unroll
    for (int mi = 0; mi < 4; ++mi)
      af[mi] = *reinterpret_cast<const bf16x8*>(&lA[wm + mi * 16 + l16][kb]);
    #pragma unroll
    for (int ni = 0; ni < 2; ++ni)
      bfr[ni] = *reinterpret_cast<const bf16x8*>(&lB[wn + ni * 16 + l16][kb]);
    #pragma unroll
    for (int mi = 0; mi < 4; ++mi)
      #pragma unroll
      for (int ni = 0; ni < 2; ++ni)
        acc[mi][ni] = __builtin_amdgcn_mfma_f32_16x16x32_bf16(af[mi], bfr[ni], acc[mi][ni], 0, 0, 0);
  }
  // transposed output: 4 consecutive rows per lane -> one 8B store
  if (Yt) {
    #pragma unroll
    for (int mi = 0; mi < 4; ++mi)
      #pragma unroll
      for (int ni = 0; ni < 2; ++ni) {
        long rowb = rowA0 + wm + mi * 16 + quad * 4;
        long col = rowB0 + wn + ni * 16 + l16;
        bf16 t4[4];
        #pragma unroll
        for (int r = 0; r < 4; ++r) t4[r] = __float2bfloat16(acc[mi][ni][r]);
        *reinterpret_cast<ushort4*>(Yt + col * (long)NN + rowb) =
            *reinterpret_cast<const ushort4*>(t4);
      }
  }
  // row-major output via LDS bounce (reuse lA scratch; MFMA reads are done)
  __syncthreads();
  bf16 (*cs)[72] = reinterpret_cast<bf16(*)[72]>(sm);   // 128x72x2B = 18.4 KB
  #pragma unroll
  for (int mi = 0; mi < 4; ++mi)
    #pragma unroll
    for (int ni = 0; ni < 2; ++ni)
      #pragma unroll
      for (int r = 0; r < 4; ++r)
        cs[wm + mi * 16 + quad * 4 + r][wn + ni * 16 + l16] = __float2bfloat16(acc[mi][ni][r]);
  __syncthreads();
  #pragma unroll
  for (int i = 0; i < 4; ++i) {
    int f = tid + i * 256;          // 1024 segments = 128 rows x 8 (8-col) segs
    int r = f >> 3, sg = f & 7;
    *reinterpret_cast<uint4*>(RM + (rowA0 + r) * rm_ld + rowB0 + sg * 8) =
        *reinterpret_cast<const uint4*>(&cs[r][sg * 8]);
  }
}

// ---------------- symmetric S GEMM body: S = relu(Xn @ Xn^T), tile (bi,bj) ------
// sm: >= 2*128*136*2 bytes. Triangular work (bj>=bi); both copies stored via
// coalesced dwordx4 through dual LDS bounce; mirror values bit-identical.
__device__ __forceinline__ void gemm_s_sym_body(const bf16* __restrict__ Xn,
                                                bf16* __restrict__ S,
                                                int bi, int bj, int tid, bf16* sm) {
  if (bj < bi) return;                 // lower triangle via mirror stores
  bf16 (*lA)[136] = reinterpret_cast<bf16(*)[136]>(sm);
  bf16 (*lB)[136] = reinterpret_cast<bf16(*)[136]>(sm + 128 * 136);
  long rowA0 = (long)bi * 128, rowB0 = (long)bj * 128;
  for (int i = 0; i < 8; ++i) {
    int f = tid + i * 256;
    int r = f >> 4, kg = f & 15;
    *reinterpret_cast<uint4*>(&lA[r][kg * 8]) =
        *reinterpret_cast<const uint4*>(Xn + (rowA0 + r) * DD + kg * 8);
    *reinterpret_cast<uint4*>(&lB[r][kg * 8]) =
        *reinterpret_cast<const uint4*>(Xn + (rowB0 + r) * DD + kg * 8);
  }
  __syncthreads();
  int wave = tid >> 6, lane = tid & 63;
  int wm = (wave >> 1) * 64;
  int wn = (wave & 1) * 64;
  int quad = lane >> 4, l16 = lane & 15;
  f32x4 acc[4][4];
  #pragma unroll
  for (int mi = 0; mi < 4; ++mi)
    #pragma unroll
    for (int ni = 0; ni < 4; ++ni) acc[mi][ni] = {0.f, 0.f, 0.f, 0.f};
  #pragma unroll
  for (int ks = 0; ks < 4; ++ks) {
    int kb = ks * 32 + quad * 8;
    bf16x8 af[4], bfr[4];
    #pragma unroll
    for (int mi = 0; mi < 4; ++mi)
      af[mi] = *reinterpret_cast<const bf16x8*>(&lA[wm + mi * 16 + l16][kb]);
    #pragma unroll
    for (int ni = 0; ni < 4; ++ni)
      bfr[ni] = *reinterpret_cast<const bf16x8*>(&lB[wn + ni * 16 + l16][kb]);
    #pragma unroll
    for (int mi = 0; mi < 4; ++mi)
      #pragma unroll
      for (int ni = 0; ni < 4; ++ni)
        acc[mi][ni] = __builtin_amdgcn_mfma_f32_16x16x32_bf16(af[mi], bfr[ni], acc[mi][ni], 0, 0, 0);
  }
  // relu once; keep bf16 quads for both bounce paths
  ushort4 q4[4][4];                    // [mi][ni] = 4 consecutive rows (quad)
  #pragma unroll
  for (int mi = 0; mi < 4; ++mi)
    #pragma unroll
    for (int ni = 0; ni < 4; ++ni) {
      unsigned short t4[4];
      #pragma unroll
      for (int r = 0; r < 4; ++r) {
        float vv = acc[mi][ni][r];
        vv = vv > 0.f ? vv : 0.f;
        bf16 b = __float2bfloat16(vv);
        t4[r] = *reinterpret_cast<unsigned short*>(&b);
      }
      q4[mi][ni] = *reinterpret_cast<const ushort4*>(t4);
    }
  __syncthreads();   // all waves' MFMA LDS reads done; reuse lA=cs, lB=csT
  bf16 (*cs)[136]  = lA;
  bf16 (*csT)[136] = lB;
  #pragma unroll
  for (int mi = 0; mi < 4; ++mi)
    #pragma unroll
    for (int ni = 0; ni < 4; ++ni) {
      int row = wm + mi * 16 + quad * 4;
      int col = wn + ni * 16 + l16;
      const unsigned short* t4 = reinterpret_cast<const unsigned short*>(&q4[mi][ni]);
      #pragma unroll
      for (int r = 0; r < 4; ++r)
        *reinterpret_cast<unsigned short*>(&cs[row + r][col]) = t4[r];
      *reinterpret_cast<ushort4*>(&csT[col][row]) = q4[mi][ni];
    }
  __syncthreads();
  #pragma unroll
  for (int i = 0; i < 8; ++i) {
    int f = tid + i * 256;          // 2048 segments = 128 rows x 16 (8-col) segs
    int r = f >> 4, sg = f & 15;
    *reinterpret_cast<uint4*>(S + (rowA0 + r) * NN + rowB0 + sg * 8) =
        *reinterpret_cast<const uint4*>(&cs[r][sg * 8]);
  }
  if (bi != bj) {
    #pragma unroll
    for (int i = 0; i < 8; ++i) {
      int f = tid + i * 256;        // mirror tile rows = global rows rowB0..+127
      int r = f >> 4, sg = f & 15;
      *reinterpret_cast<uint4*>(S + (rowB0 + r) * NN + rowA0 + sg * 8) =
          *reinterpret_cast<const uint4*>(&csT[r][sg * 8]);
    }
  }
}

// ---------------- MERGED launch: S-GEMM tiles + both Y GEMMs ----------------
__launch_bounds__(256)
__global__ void gemm_sy(const bf16* __restrict__ Xn, bf16* __restrict__ S,
                        const bf16* __restrict__ xb,
                        const bf16* __restrict__ Wt1, const bf16* __restrict__ Wt2,
                        bf16* __restrict__ Yt1, bf16* __restrict__ Yt2,
                        bf16* __restrict__ Yr1, bf16* __restrict__ Yr2) {
  __shared__ bf16 smem[2 * 128 * 136];   // 69632 B
  if (blockIdx.x < 64) {
    gemm_s_sym_body(Xn, S, blockIdx.y, blockIdx.x, threadIdx.x, smem);
  } else {
    int q = blockIdx.x - 64;             // 0..3: {Y1,Y1,Y2,Y2} x col-half
    int sel = q >> 1, bx = q & 1;
    gemm_core(xb, sel ? Wt2 : Wt1, (long)blockIdx.y * 128, (long)bx * 64, threadIdx.x,
              sel ? Yt2 : Yt1, sel ? Yr2 : Yr1, DD, smem);
  }
}

// ---------------- top-k histogram body (single-copy per-wave LDS histogram) -----
// Round-9 verified form (17408 B/block -> 8 blocks/CU). Round-11's dual-copy
// variant halved bank conflicts but halved occupancy on this LATENCY-bound
// kernel -> net regression. Keep the small footprint.
__device__ __forceinline__ void topk_body(const bf16* __restrict__ S,
                                          unsigned short* __restrict__ kthr,
                                          float* __restrict__ invRsF,
                                          int bid, int tid, unsigned* hist) {
  int wave = tid >> 6, lane = tid & 63;
  long row = (long)bid * 4 + wave;
  unsigned* h = hist + wave * 1088;    // 17 bins/lane; bins 1025..1087 stay zero
  #pragma unroll
  for (int j = 0; j < 17; ++j) h[lane + j * 64] = 0;
  __syncthreads();

  const uint4* rp = reinterpret_cast<const uint4*>(S + row * NN) + lane;
  unsigned hs = 0;                      // or-accumulator: detects values >= 0x4000
  #pragma unroll
  for (int t = 0; t < 16; ++t) {
    uint4 v = rp[t * 64];
    unsigned a4[4] = {v.x, v.y, v.z, v.w};
    #pragma unroll
    for (int e = 0; e < 4; ++e) {
      unsigned u = a4[e];
      hs |= u;
      // packed per-half: clamp((s16)v - 0x3BFF, 0, 1024)
      s16x2 d = __builtin_bit_cast(s16x2, u) - __builtin_bit_cast(s16x2, 0x3BFF3BFFu);
      d = __builtin_elementwise_max(d, (s16x2)0);
      d = __builtin_elementwise_min(d, (s16x2)1024);
      unsigned bins = __builtin_bit_cast(unsigned, d);
      unsigned blo = bins & 0xFFFFu, bhi = bins >> 16;
      if (blo) atomicAdd(&h[blo], 1u);
      if (bhi) atomicAdd(&h[bhi], 1u);
    }
  }
  __syncthreads();   // own-wave atomics complete (conservative; deps are intra-wave)

  // per-lane owned bins [lane*17, lane*17+17): counts + local suffix sums
  unsigned c[17], sfx[17];
  #pragma unroll
  for (int j = 0; j < 17; ++j) c[j] = h[lane * 17 + j];
  unsigned run = 0;
  #pragma unroll
  for (int j = 16; j >= 0; --j) { run += c[j]; sfx[j] = run; }
  // inclusive suffix-scan of per-lane totals across lanes
  unsigned incl = sfx[0];
  #pragma unroll
  for (int off = 1; off < 64; off <<= 1) {
    unsigned t = __shfl_down(incl, off);
    incl += (lane + off < 64) ? t : 0u;
  }
  unsigned above = incl - sfx[0];       // total count in bins owned by lanes > lane
  // largest bin (>=1) with suffix-count >= KTOP
  int cand = -1;
  #pragma unroll
  for (int j = 16; j >= 0; --j) {
    int b = lane * 17 + j;
    if (cand < 0 && b >= 1 && above + sfx[j] >= (unsigned)KTOP) cand = b;
  }
  int best = cand;
  #pragma unroll
  for (int off = 1; off < 64; off <<= 1) {
    int t = __shfl_xor(best, off);
    best = t > best ? t : best;
  }
  int thrbin = best >= 1 ? best : 1;    // no qualifying bin -> thr = 0x3C00
  unsigned thr = 0x3BFFu + (unsigned)thrbin;

  // rowsum = sum over kept bins of count * value (exact)
  float fs = 0.f;
  #pragma unroll
  for (int j = 0; j < 17; ++j) {
    int b = lane * 17 + j;
    float val = __uint_as_float((0x3BFFu + (unsigned)b) << 16);
    fs += (b >= thrbin) ? (float)c[j] * val : 0.f;
  }
  // cold path (never taken for this problem): values >= 0x4000 clamped to bin 1024
  if (__ballot(hs & 0x40004000u)) {
    float v1024 = __uint_as_float(0x3FFF0000u);
    #pragma unroll 1
    for (int t = 0; t < 16; ++t) {
      uint4 v = rp[t * 64];
      unsigned a4[4] = {v.x, v.y, v.z, v.w};
      for (int e = 0; e < 4; ++e) {
        unsigned lo = a4[e] & 0xFFFFu, hi = a4[e] >> 16;
        if (lo >= 0x4000u && lo < 0x8000u) fs += __uint_as_float(lo << 16) - v1024;
        if (hi >= 0x4000u && hi < 0x8000u) fs += __uint_as_float(hi << 16) - v1024;
      }
    }
  }
  #pragma unroll
  for (int off = 1; off < 64; off <<= 1) fs += __shfl_xor(fs, off);
  if (lane == 0) {
    invRsF[row] = 1.0f / (fs + 1.0f);
    kthr[row] = (unsigned short)thr;    // raw positive bf16 pattern
  }
}

// ---------------- rank-5 prior reduce body ----------------
__device__ __forceinline__ void prior_reduce_body(const float* __restrict__ impf,
                                                  const bf16* __restrict__ Yt1,
                                                  float* __restrict__ Mt, float* __restrict__ Gt,
                                                  int c, int tid, float* red /*[5][4]*/) {
  float s[5] = {0.f, 0.f, 0.f, 0.f, 0.f};
  bool hasY = (c < 128);
  const bf16* col = Yt1 + (long)(hasY ? c : 0) * NN;
  for (int j = tid; j < NN; j += 256) {
    float d = impf[j];
    float a = __expf(d * d * (-1.0f / 32.0f));
    float p = hasY ? a * __bfloat162float(col[j]) : a;
    #pragma unroll
    for (int t = 0; t < 5; ++t) { s[t] += p; p *= d; }
  }
  #pragma unroll
  for (int t = 0; t < 5; ++t)
    for (int off = 1; off < 64; off <<= 1) s[t] += __shfl_xor(s[t], off);
  int wave = tid >> 6, lane = tid & 63;
  if (lane == 0)
    #pragma unroll
    for (int t = 0; t < 5; ++t) red[t * 4 + wave] = s[t];
  __syncthreads();
  if (tid == 0) {
    #pragma unroll
    for (int t = 0; t < 5; ++t) {
      float v = red[t * 4 + 0] + red[t * 4 + 1] + red[t * 4 + 2] + red[t * 4 + 3];
      if (hasY) Mt[t * 128 + c] = v; else Gt[t] = v;
    }
  }
}

// ---------------- MERGED launch: top-k rows + prior reduce ----------------
__launch_bounds__(256)
__global__ void prior_topk(const float* __restrict__ impf, const bf16* __restrict__ Yt1,
                           float* __restrict__ Mt, float* __restrict__ Gt,
                           const bf16* __restrict__ S, unsigned short* __restrict__ kthr,
                           float* __restrict__ invRsF) {
  __shared__ unsigned smem[4 * 1088];   // 17408 B (topk hist; prior uses 20 floats)
  int bid = blockIdx.x;
  if (bid < NN / 4) {
    topk_body(S, kthr, invRsF, bid, threadIdx.x, smem);
  } else {
    prior_reduce_body(impf, Yt1, Mt, Gt, bid - NN / 4, threadIdx.x,
                      reinterpret_cast<float*>(smem));
  }
}

// ---------------- split-K masked AV GEMM: Pacc[s] = (mask(S) @ Y2) over k-slice s ----
__launch_bounds__(256)
__global__ void fused_av_partial(const bf16* __restrict__ S, const bf16* __restrict__ Yt2,
                                 const unsigned short* __restrict__ kthr,
                                 float* __restrict__ Pacc) {
  __shared__ bf16 lS[2][128][64];   // 16 KB per buffer
  __shared__ bf16 lY[2][128][64];   // 16 KB per buffer
  int tid = threadIdx.x;
  int wave = tid >> 6, lane = tid & 63;
  long row0 = (long)blockIdx.x * 128;
  long kbase = (long)blockIdx.y * KCH;
  int quad = lane >> 4, l16 = lane & 15;
  int wm = (wave >> 1) * 64;
  int wn = (wave & 1) * 64;
  int swz = (l16 & 7) << 4;                       // read-side XOR swizzle (bytes)

  int sj = lane >> 3, sseg = lane & 7;
  long swb = (long)((sseg ^ sj) << 4);
  const char* gS[4];
  const char* gY[4];
  #pragma unroll
  for (int j = 0; j < 4; ++j) {
    long srow = row0 + (long)(wave * 4 + j) * 8 + sj;
    gS[j] = (const char*)S + (srow * NN + kbase) * 2 + swb;
    long ycol = (long)(wave * 4 + j) * 8 + sj;
    gY[j] = (const char*)Yt2 + (ycol * (long)NN + kbase) * 2 + swb;
  }
  unsigned pp[4];
  #pragma unroll
  for (int mi = 0; mi < 4; ++mi) {
    unsigned p = kthr[row0 + wm + mi * 16 + l16];
    pp[mi] = (p << 16) | p;
  }
  f32x4 acc[4][4];
  #pragma unroll
  for (int mi = 0; mi < 4; ++mi)
    #pragma unroll
    for (int ni = 0; ni < 4; ++ni) acc[mi][ni] = {0.f, 0.f, 0.f, 0.f};

  constexpr int NT = KCH / 64;   // 16 K-steps
  {
    char* lsb = (char*)&lS[0][0][0];
    char* lyb = (char*)&lY[0][0][0];
    #pragma unroll
    for (int j = 0; j < 4; ++j) { gll16(gS[j], lsb + (wave * 4 + j) * 1024); gS[j] += 128; }
    #pragma unroll
    for (int j = 0; j < 4; ++j) { gll16(gY[j], lyb + (wave * 4 + j) * 1024); gY[j] += 128; }
  }
  #pragma unroll 1
  for (int t = 0; t < NT; ++t) {
    int cur = t & 1;
    if (t + 1 < NT) {
      char* lsb = (char*)&lS[cur ^ 1][0][0];
      char* lyb = (char*)&lY[cur ^ 1][0][0];
      #pragma unroll
      for (int j = 0; j < 4; ++j) { gll16(gS[j], lsb + (wave * 4 + j) * 1024); gS[j] += 128; }
      #pragma unroll
      for (int j = 0; j < 4; ++j) { gll16(gY[j], lyb + (wave * 4 + j) * 1024); gY[j] += 128; }
      asm volatile("s_waitcnt vmcnt(8)" ::: "memory");   // current tile landed; 8 in flight
    } else {
      asm volatile("s_waitcnt vmcnt(0)" ::: "memory");
    }
    __builtin_amdgcn_s_barrier();
    const char* lsb = (const char*)&lS[cur][0][0];
    const char* lyb = (const char*)&lY[cur][0][0];
    #pragma unroll
    for (int ks = 0; ks < 2; ++ks) {
      int cb = ks * 64 + quad * 16;
      int cbs = cb ^ swz;
      bf16x8 av[4], bv[4];
      #pragma unroll
      for (int mi = 0; mi < 4; ++mi) {
        int r = wm + mi * 16 + l16;
        u32x4 uu = *reinterpret_cast<const u32x4*>(lsb + r * 128 + cbs);
        #pragma unroll
        for (int e = 0; e < 4; ++e) {
          unsigned tb = uu[e] | 0x80008000u;
          u16x2 d = __builtin_bit_cast(u16x2, tb) - __builtin_bit_cast(u16x2, pp[mi]);
          s16x2 msk = __builtin_bit_cast(s16x2, d) >> 15;   // 0xFFFF if kept (u>=p)
          uu[e] &= __builtin_bit_cast(unsigned, msk);
        }
        av[mi] = __builtin_bit_cast(bf16x8, uu);
      }
      #pragma unroll
      for (int ni = 0; ni < 4; ++ni) {
        int c = wn + ni * 16 + l16;
        bv[ni] = *reinterpret_cast<const bf16x8*>(lyb + c * 128 + cbs);
      }
      #pragma unroll
      for (int mi = 0; mi < 4; ++mi)
        #pragma unroll
        for (int ni = 0; ni < 4; ++ni)
          acc[mi][ni] = __builtin_amdgcn_mfma_f32_16x16x32_bf16(av[mi], bv[ni], acc[mi][ni], 0, 0, 0);
    }
    __builtin_amdgcn_s_barrier();   // all waves done reading cur before it is re-staged
  }
  float* out = Pacc + (long)blockIdx.y * NN * DD;
  #pragma unroll
  for (int mi = 0; mi < 4; ++mi)
    #pragma unroll
    for (int ni = 0; ni < 4; ++ni)
      #pragma unroll
      for (int r = 0; r < 4; ++r) {
        long row = row0 + wm + mi * 16 + quad * 4 + r;
        int col = wn + ni * 16 + l16;
        out[row * DD + col] = acc[mi][ni][r];
      }
}

// ---------------- epilogue: reduce partials + prior (inline pvec) + leaky ----------
__global__ void epilogue(const float* __restrict__ Pacc, const bf16* __restrict__ Yr1,
                         const bf16* __restrict__ Yr2, const float* __restrict__ Gt,
                         const float* __restrict__ Mt, const float* __restrict__ invRsF,
                         const float* __restrict__ impf,
                         float* __restrict__ Xout, const float* __restrict__ hres,
                         float* __restrict__ outf) {
  int q = blockIdx.x * 256 + threadIdx.x;   // one f32x4 group per thread
  int row = q >> 5, c4 = (q & 31) << 2;
  long i = (long)row * DD + c4;
  f32x4 a4 = {0.f, 0.f, 0.f, 0.f};
  #pragma unroll
  for (int s = 0; s < KSLICE; ++s)
    a4 += *reinterpret_cast<const f32x4*>(&Pacc[((long)s * NN + row) * DD + c4]);
  float d = impf[row];
  float a = __expf(d * d * (-1.0f / 32.0f));
  const float ct[5] = {1.0f, 1.0f / 16.0f, 1.0f / 512.0f, 1.0f / 24576.0f, 1.0f / 1572864.0f};
  float g[5];
  float p = a;
  #pragma unroll
  for (int t = 0; t < 5; ++t) { g[t] = ct[t] * p; p *= d; }
  float rs = 1.0f;  // + eye
  #pragma unroll
  for (int t = 0; t < 5; ++t) rs += g[t] * Gt[t];
  float inv = 1.0f / rs;
  float pv[5];
  #pragma unroll
  for (int t = 0; t < 5; ++t) pv[t] = g[t] * inv;
  float ir = invRsF[row];
  ushort4 y1u = *reinterpret_cast<const ushort4*>(Yr1 + i);
  ushort4 y2u = *reinterpret_cast<const ushort4*>(Yr2 + i);
  const bf16* y1p = reinterpret_cast<const bf16*>(&y1u);
  const bf16* y2p = reinterpret_cast<const bf16*>(&y2u);
  f32x4 res;
  #pragma unroll
  for (int k = 0; k < 4; ++k) {
    float y1 = __bfloat162float(y1p[k]);
    float y2 = __bfloat162float(y2p[k]);
    int col = c4 + k;
    float prior = inv * y1 + pv[0] * Mt[col] + pv[1] * Mt[128 + col] + pv[2] * Mt[256 + col]
                + pv[3] * Mt[384 + col] + pv[4] * Mt[512 + col];
    float v = prior + ir * (a4[k] + y2);
    v = v > 0.f ? v : 0.01f * v;
    res[k] = v;
  }
  if (outf) {
    f32x4 h4 = *reinterpret_cast<const f32x4*>(&hres[i]);
    #pragma unroll
    for (int k = 0; k < 4; ++k) res[k] = res[k] + h4[k] * d;   // d == impf[row]
    *reinterpret_cast<f32x4*>(&outf[i]) = res;
  } else {
    *reinterpret_cast<f32x4*>(&Xout[i]) = res;
  }
}

// ---------------- host ----------------

extern "C" void kernel_launch(void* const* d_in, const int* in_sizes, int n_in,
                              void* d_out, int out_size, void* d_ws, size_t ws_size,
                              hipStream_t stream) {
  const void* x_in   = d_in[0];
  const void* imp_in = d_in[1];
  const void* W1 = d_in[2];
  const void* W2 = d_in[3];
  float* out = (float*)d_out;

  char* ws = (char*)d_ws;
  size_t o = 0;
  auto alloc = [&](size_t bytes) { void* p = ws + o; o += (bytes + 511) & ~511ull; return p; };
  bf16*  Af   = (bf16*)alloc((size_t)NN * NN * 2);    // 134 MB relu'd similarity S
  float* Pacc = (float*)alloc((size_t)KSLICE * NN * DD * 4);  // 32 MB split-K partials
  float* xf1  = (float*)alloc((size_t)NN * DD * 4);   // layer-0 output (= h for residual)
  bf16*  xnb  = (bf16*)alloc((size_t)NN * DD * 2);
  bf16*  xb   = (bf16*)alloc((size_t)NN * DD * 2);
  bf16*  Yt1  = (bf16*)alloc((size_t)NN * DD * 2);    // [128][8192] (x@W1)^T
  bf16*  Yt2  = (bf16*)alloc((size_t)NN * DD * 2);
  bf16*  Yr1  = (bf16*)alloc((size_t)NN * DD * 2);    // [8192][128] row-major copies
  bf16*  Yr2  = (bf16*)alloc((size_t)NN * DD * 2);
  bf16*  Wt1  = (bf16*)alloc((size_t)2 * DD * DD * 2);
  bf16*  Wt2  = (bf16*)alloc((size_t)2 * DD * DD * 2);
  float* impf = (float*)alloc((size_t)NN * 4);
  float* Mt   = (float*)alloc((size_t)5 * 128 * 4);
  float* Gt   = (float*)alloc((size_t)8 * 4);
  float* invRsF = (float*)alloc((size_t)NN * 4);
  unsigned short* kthr = (unsigned short*)alloc((size_t)NN * 2);
  int*   dflag  = (int*)alloc(64);
  (void)ws_size; (void)n_in; (void)in_sizes; (void)out_size;

  prep<<<5, 256, 0, stream>>>((const unsigned short*)x_in, imp_in, W1, W2,
                              impf, Wt1, Wt2, dflag);

  for (int l = 0; l < 2; ++l) {
    rownorm<<<NN / 4, 256, 0, stream>>>(l ? (const void*)xf1 : x_in, dflag, l ? 0 : 1, xnb, xb);
    gemm_sy<<<dim3(68, 64), 256, 0, stream>>>(xnb, Af, xb,
                                              Wt1 + l * DD * DD, Wt2 + l * DD * DD,
                                              Yt1, Yt2, Yr1, Yr2);
    prior_topk<<<NN / 4 + 129, 256, 0, stream>>>(impf, Yt1, Mt, Gt, Af, kthr, invRsF);
    fused_av_partial<<<dim3(NN / 128, KSLICE), 256, 0, stream>>>(Af, Yt2, kthr, Pacc);
    if (l == 0)
      epilogue<<<NN * DD / 1024, 256, 0, stream>>>(Pacc, Yr1, Yr2, Gt, Mt, invRsF, impf,
                                                   xf1, nullptr, nullptr);
    else
      epilogue<<<NN * DD / 1024, 256, 0, stream>>>(Pacc, Yr1, Yr2, Gt, Mt, invRsF, impf,
                                                   nullptr, xf1, out);
  }
}